// Round 3
// baseline (558.961 us; speedup 1.0000x reference)
//
#include <hip/hip_runtime.h>
#include <hip/hip_cooperative_groups.h>
#include <math.h>

namespace cg = cooperative_groups;

#define L_TOTAL 65536
#define D_DIM   256

typedef float vf4 __attribute__((ext_vector_type(4)));

// ================= fused cooperative kernel ================================
// 1024 blocks x 256 threads; block b owns rows [64b, 64b+64).
// Wave w owns rows [16w,16w+16); lane l owns cols [4l,4l+4).
// V stays in registers across all three phases (read once).
#define NB    1024      // blocks
#define RB    64        // rows per block
#define NSUP  32        // supers
#define SBLK  32        // blocks per super

__global__ __launch_bounds__(256, 4) void kFused(
    const float* __restrict__ K, const float* __restrict__ V,
    const float* __restrict__ q,
    float* __restrict__ cm, float* __restrict__ cu,
    float* __restrict__ cw, float* __restrict__ T,
    float* __restrict__ out)
{
    const int t = threadIdx.x;
    const int b = blockIdx.x;
    const int S = b >> 5;          // super index
    const int jloc = b & 31;       // position within super
    const int r0 = b * RB;
    const int wave = t >> 6, lane = t & 63;

    __shared__ float s_lds[RB];
    __shared__ vf4  wbuf[4][64];           // phase1: partial-w; phase3: segments
    __shared__ float Lm[256], Lu[256];
    __shared__ float pmL[NB + 1], puL[NB + 1];
    __shared__ float sa[RB], se[RB], sri[RB];
    __shared__ vf4  seedL[64];
    __shared__ float asL[4];

    // ---------------- phase 1: block aggregates -----------------------------
    vf4 v4[16];
    {
        const vf4* Vp = reinterpret_cast<const vf4*>(V + (size_t)(r0 + wave * 16) * D_DIM) + lane;
        #pragma unroll
        for (int k = 0; k < 16; ++k) v4[k] = Vp[(size_t)k * (D_DIM / 4)];

        const vf4 q4 = *reinterpret_cast<const vf4*>(q + 4 * lane);
        const vf4* Kp = reinterpret_cast<const vf4*>(K + (size_t)(r0 + wave * 16) * D_DIM) + lane;
        #pragma unroll
        for (int k = 0; k < 16; ++k) {
            const vf4 kv = __builtin_nontemporal_load(Kp + (size_t)k * (D_DIM / 4));
            float d = kv.x * q4.x + kv.y * q4.y + kv.z * q4.z + kv.w * q4.w;
            #pragma unroll
            for (int off = 32; off > 0; off >>= 1) d += __shfl_xor(d, off, 64);
            if (lane == 0) s_lds[wave * 16 + k] = d;
        }
    }
    __syncthreads();

    float m_b = -INFINITY;
    #pragma unroll
    for (int j = 0; j < RB; ++j) m_b = fmaxf(m_b, s_lds[j]);
    float u_b = 0.f;
    #pragma unroll
    for (int j = 0; j < RB; ++j) u_b += __expf(s_lds[j] - m_b);

    {
        vf4 pw = {0.f, 0.f, 0.f, 0.f};
        #pragma unroll
        for (int k = 0; k < 16; ++k)
            pw = pw + __expf(s_lds[wave * 16 + k] - m_b) * v4[k];
        wbuf[wave][lane] = pw;
    }
    __syncthreads();
    if (t < 64) {
        const vf4 w4 = (wbuf[0][t] + wbuf[1][t]) + (wbuf[2][t] + wbuf[3][t]);
        reinterpret_cast<vf4*>(cw)[(size_t)b * 64 + t] = w4;
    }
    if (t == 0) { cm[b] = m_b; cu[b] = u_b; }

    __threadfence();
    cg::this_grid().sync();

    // ---------------- phase 2a: redundant scalar (m,u) scan of 1024 ---------
    float am[4], au[4];
    float M = -INFINITY, U = 0.f;
    #pragma unroll
    for (int j = 0; j < 4; ++j) {
        am[j] = cm[4 * t + j]; au[j] = cu[4 * t + j];
        const float mm = fmaxf(M, am[j]);
        U = U * __expf(M - mm) + au[j] * __expf(am[j] - mm);
        M = mm;
    }
    Lm[t] = M; Lu[t] = U;
    float Mi = M, Ui = U;
    __syncthreads();
    for (int off = 1; off < 256; off <<= 1) {
        float m1 = 0.f, u1 = 0.f;
        const bool act = (t >= off);
        if (act) { m1 = Lm[t - off]; u1 = Lu[t - off]; }
        __syncthreads();
        if (act) {
            const float mm = fmaxf(m1, Mi);
            Ui = u1 * __expf(m1 - mm) + Ui * __expf(Mi - mm);
            Mi = mm;
            Lm[t] = Mi; Lu[t] = Ui;
        }
        __syncthreads();
    }
    float Me = (t == 0) ? -INFINITY : Lm[t - 1];
    float Ue = (t == 0) ? 0.f : Lu[t - 1];
    #pragma unroll
    for (int j = 0; j < 4; ++j) {
        pmL[4 * t + j] = Me; puL[4 * t + j] = Ue;
        const float mm = fmaxf(Me, am[j]);
        Ue = Ue * __expf(Me - mm) + au[j] * __expf(am[j] - mm);
        Me = mm;
    }
    if (t == 255) { pmL[NB] = Me; puL[NB] = Ue; }
    __syncthreads();

    // ---------------- phase 2b: blocks 0..31 compute super totals T ----------
    if (b < NSUP && t < 64) {
        vf4 PW = {0.f, 0.f, 0.f, 0.f};
        const vf4* cw4 = reinterpret_cast<const vf4*>(cw);
        #pragma unroll 8
        for (int j = 0; j < SBLK; ++j) {
            const int bb = b * SBLK + j;
            const float caj = __expf(pmL[bb] - pmL[bb + 1]);   // bb=0: exp(-inf)=0
            const float cbj = __expf(cm[bb] - pmL[bb + 1]);
            PW = PW * caj + cw4[(size_t)bb * 64 + t] * cbj;
        }
        reinterpret_cast<vf4*>(T)[(size_t)b * 64 + t] = PW;
    }
    __threadfence();
    cg::this_grid().sync();

    // ---------------- phase 3: prefix folds + row scan + output --------------
    if (wave == 0) {
        // 64-row shuffle scan (lanes = rows), seeded by (pmL[b], puL[b])
        const float pmc = pmL[b], puc = puL[b];
        const float s_val = s_lds[lane];
        float m = s_val, u = 1.0f;
        #pragma unroll
        for (int off = 1; off < 64; off <<= 1) {
            const float m1 = __shfl_up(m, off, 64);
            const float u1 = __shfl_up(u, off, 64);
            if (lane >= off) {
                const float mm = fmaxf(m1, m);
                u = u1 * __expf(m1 - mm) + u * __expf(m - mm);
                m = mm;
            }
        }
        const float m_row = fmaxf(pmc, m);
        const float u_row = puc * __expf(pmc - m_row) + u * __expf(m - m_row);
        const float mpr = __shfl_up(m_row, 1, 64);
        const float m_prev = (lane == 0) ? pmc : mpr;
        sa[lane]  = __expf(m_prev - m_row);    // row0 of block0: exp(-inf)=0
        se[lane]  = __expf(s_val - m_row);
        sri[lane] = 1.0f / u_row;
    } else if (wave == 1) {
        // exclusive vector prefix for this block, per column-quad = lane
        const float pmc = pmL[b];
        const float pmS = pmL[S * SBLK];
        const vf4* cw4 = reinterpret_cast<const vf4*>(cw);
        vf4 PW = {0.f, 0.f, 0.f, 0.f};
        for (int j = 0; j < jloc; ++j) {
            const int bb = S * SBLK + j;
            const float caj = __expf(pmL[bb] - pmL[bb + 1]);
            const float cbj = __expf(cm[bb] - pmL[bb + 1]);
            PW = PW * caj + cw4[(size_t)bb * 64 + lane] * cbj;
        }
        const vf4* T4 = reinterpret_cast<const vf4*>(T);
        vf4 SW = {0.f, 0.f, 0.f, 0.f};
        for (int Sp = 0; Sp < S; ++Sp) {
            const float g = __expf(pmL[Sp * SBLK] - pmL[Sp * SBLK + SBLK]); // S'=0: 0
            SW = SW * g + T4[(size_t)Sp * 64 + lane];
        }
        const float gf = (b == 0) ? 0.f : __expf(pmS - pmc);
        seedL[lane] = SW * gf + PW;
    }
    __syncthreads();

    // 4-segment vector recurrence: pass1 zero-init, combine, pass2 emit
    vf4 B = {0.f, 0.f, 0.f, 0.f};
    float A = 1.f;
    #pragma unroll
    for (int k = 0; k < 16; ++k) {
        const int j = wave * 16 + k;
        B = B * sa[j] + v4[k] * se[j];
        A *= sa[j];
    }
    wbuf[wave][lane] = B;
    if (lane == 0) asL[wave] = A;
    __syncthreads();

    vf4 W = seedL[lane];
    for (int p = 0; p < wave; ++p)
        W = W * asL[p] + wbuf[p][lane];

    float* Op = out + (size_t)(r0 + wave * 16) * D_DIM + 4 * lane;
    #pragma unroll
    for (int k = 0; k < 16; ++k) {
        const int j = wave * 16 + k;
        W = W * sa[j] + v4[k] * se[j];
        __builtin_nontemporal_store(W * sri[j],
                                    reinterpret_cast<vf4*>(Op + (size_t)k * D_DIM));
    }
}

// ================= fallback path (proven 3-kernel pipeline) ================
#define C_ROWS  32
#define N_CHUNK (L_TOTAL / C_ROWS)    // 2048
#define SUPER   32
#define N_SUPER (N_CHUNK / SUPER)     // 64

__global__ __launch_bounds__(256) void kA_aggregate(
    const float* __restrict__ K, const float* __restrict__ V,
    const float* __restrict__ q,
    float* __restrict__ s_g, float* __restrict__ cm,
    float* __restrict__ cu, float* __restrict__ cw)
{
    const int t = threadIdx.x;
    const int c = blockIdx.x;
    const int r0 = c * C_ROWS;
    const int wave = t >> 6, lane = t & 63;

    __shared__ float s_lds[C_ROWS];
    __shared__ vf4  pw_lds[4][64];

    vf4 v4[8];
    const vf4* Vp = reinterpret_cast<const vf4*>(V + (size_t)(r0 + wave * 8) * D_DIM) + lane;
    #pragma unroll
    for (int k = 0; k < 8; ++k) v4[k] = Vp[(size_t)k * (D_DIM / 4)];

    const vf4 q4 = *reinterpret_cast<const vf4*>(q + 4 * lane);
    const vf4* Kp = reinterpret_cast<const vf4*>(K + (size_t)(r0 + wave * 8) * D_DIM) + lane;
    #pragma unroll
    for (int k = 0; k < 8; ++k) {
        const vf4 kv = __builtin_nontemporal_load(Kp + (size_t)k * (D_DIM / 4));
        float d = kv.x * q4.x + kv.y * q4.y + kv.z * q4.z + kv.w * q4.w;
        #pragma unroll
        for (int off = 32; off > 0; off >>= 1) d += __shfl_xor(d, off, 64);
        if (lane == 0) s_lds[wave * 8 + k] = d;
    }
    __syncthreads();

    if (t < C_ROWS) s_g[r0 + t] = s_lds[t];

    float m_c = -INFINITY;
    #pragma unroll
    for (int j = 0; j < C_ROWS; ++j) m_c = fmaxf(m_c, s_lds[j]);
    float u_c = 0.f;
    #pragma unroll
    for (int j = 0; j < C_ROWS; ++j) u_c += __expf(s_lds[j] - m_c);

    vf4 pw = {0.f, 0.f, 0.f, 0.f};
    #pragma unroll
    for (int k = 0; k < 8; ++k)
        pw = pw + __expf(s_lds[wave * 8 + k] - m_c) * v4[k];
    pw_lds[wave][lane] = pw;
    __syncthreads();

    if (t < 64) {
        const vf4 w4 = (pw_lds[0][t] + pw_lds[1][t]) + (pw_lds[2][t] + pw_lds[3][t]);
        reinterpret_cast<vf4*>(cw + (size_t)c * D_DIM)[t] = w4;
    }
    if (t == 0) { cm[c] = m_c; cu[c] = u_c; }
}

__global__ __launch_bounds__(256) void kCB_scan(
    const float* __restrict__ cm, const float* __restrict__ cu,
    const float* __restrict__ cw,
    float* __restrict__ pm, float* __restrict__ pu,
    float* __restrict__ gsup,
    float* __restrict__ pwl, float* __restrict__ T)
{
    const int t = threadIdx.x;
    const int S = blockIdx.x;
    __shared__ float Lm[256], Lu[256];
    __shared__ float pmL[N_CHUNK + 1];
    __shared__ float ca[SUPER], cb[SUPER];

    float am[8], au[8];
    float M = -INFINITY, U = 0.f;
    #pragma unroll
    for (int j = 0; j < 8; ++j) {
        am[j] = cm[8 * t + j]; au[j] = cu[8 * t + j];
        const float mm = fmaxf(M, am[j]);
        U = U * __expf(M - mm) + au[j] * __expf(am[j] - mm);
        M = mm;
    }
    Lm[t] = M; Lu[t] = U;
    float Mi = M, Ui = U;
    __syncthreads();
    for (int off = 1; off < 256; off <<= 1) {
        float m1 = 0.f, u1 = 0.f;
        const bool act = (t >= off);
        if (act) { m1 = Lm[t - off]; u1 = Lu[t - off]; }
        __syncthreads();
        if (act) {
            const float mm = fmaxf(m1, Mi);
            Ui = u1 * __expf(m1 - mm) + Ui * __expf(Mi - mm);
            Mi = mm;
            Lm[t] = Mi; Lu[t] = Ui;
        }
        __syncthreads();
    }
    float Me = (t == 0) ? -INFINITY : Lm[t - 1];
    float Ue = (t == 0) ? 0.f : Lu[t - 1];
    #pragma unroll
    for (int j = 0; j < 8; ++j) {
        pmL[8 * t + j] = Me;
        if (S == 0) { pm[8 * t + j] = Me; pu[8 * t + j] = Ue; }
        const float mm = fmaxf(Me, am[j]);
        Ue = Ue * __expf(Me - mm) + au[j] * __expf(am[j] - mm);
        Me = mm;
    }
    if (t == 255) {
        pmL[N_CHUNK] = Me;
        if (S == 0) { pm[N_CHUNK] = Me; pu[N_CHUNK] = Ue; }
    }
    __syncthreads();

    float wv[SUPER];
    const float* cwp = cw + (size_t)S * SUPER * D_DIM + t;
    #pragma unroll
    for (int j = 0; j < SUPER; ++j) wv[j] = cwp[(size_t)j * D_DIM];

    if (t < SUPER) {
        const int c = S * SUPER + t;
        ca[t] = __expf(pmL[c] - pmL[c + 1]);
        cb[t] = __expf(cm[c] - pmL[c + 1]);
    }
    if (t == 0)
        gsup[S] = __expf(pmL[S * SUPER] - pmL[S * SUPER + SUPER]);
    __syncthreads();

    float PW = 0.f;
    float* pwlp = pwl + (size_t)S * SUPER * D_DIM + t;
    #pragma unroll
    for (int j = 0; j < SUPER; ++j) {
        pwlp[(size_t)j * D_DIM] = PW;
        PW = PW * ca[j] + wv[j] * cb[j];
    }
    T[(size_t)S * D_DIM + t] = PW;
}

__global__ __launch_bounds__(256) void kF_output(
    const float* __restrict__ V, const float* __restrict__ s_g,
    const float* __restrict__ pm, const float* __restrict__ pu,
    const float* __restrict__ pwl, const float* __restrict__ T,
    const float* __restrict__ gsup,
    float* __restrict__ out)
{
    const int t = threadIdx.x;
    const int c = blockIdx.x;
    const int S = c / SUPER;
    const int r0 = c * C_ROWS;
    const int wave = t >> 6, lane = t & 63;

    __shared__ float sa[C_ROWS], se[C_ROWS], sri[C_ROWS];
    __shared__ vf4 seedL[64];
    __shared__ vf4 seg[4][64];
    __shared__ float asL[4];

    vf4 v4[8];
    const vf4* Vp = reinterpret_cast<const vf4*>(V + (size_t)(r0 + wave * 8) * D_DIM) + lane;
    #pragma unroll
    for (int k = 0; k < 8; ++k) v4[k] = Vp[(size_t)k * (D_DIM / 4)];

    if (wave == 0) {
        const float pmc = pm[c];
        const float puc = pu[c];
        float s_val = -INFINITY;
        if (lane < C_ROWS) s_val = s_g[r0 + lane];
        float m = s_val, u = 1.0f;
        #pragma unroll
        for (int off = 1; off < C_ROWS; off <<= 1) {
            const float m1 = __shfl_up(m, off, 32);
            const float u1 = __shfl_up(u, off, 32);
            if ((lane & 31) >= off) {
                const float mm = fmaxf(m1, m);
                u = u1 * __expf(m1 - mm) + u * __expf(m - mm);
                m = mm;
            }
        }
        const float m_row = fmaxf(pmc, m);
        const float u_row = puc * __expf(pmc - m_row) + u * __expf(m - m_row);
        const float m_prev_raw = __shfl_up(m_row, 1, 32);
        const float m_prev = ((lane & 31) == 0) ? pmc : m_prev_raw;
        if (lane < C_ROWS) {
            sa[lane]  = __expf(m_prev - m_row);
            se[lane]  = __expf(s_val - m_row);
            sri[lane] = 1.0f / u_row;
        }
    } else if (wave == 1) {
        const float pmc = pm[c];
        const float pmS = pm[S * SUPER];
        vf4 SW = {0.f, 0.f, 0.f, 0.f};
        const vf4* T4 = reinterpret_cast<const vf4*>(T) + lane;
        #pragma unroll 8
        for (int Sp = 0; Sp < S; ++Sp) {
            const float g = gsup[Sp];
            SW = SW * g + T4[(size_t)Sp * (D_DIM / 4)];
        }
        const float gf = (c == 0) ? 0.f : __expf(pmS - pmc);
        const vf4 sp = reinterpret_cast<const vf4*>(pwl + (size_t)c * D_DIM)[lane];
        seedL[lane] = SW * gf + sp;
    }
    __syncthreads();

    vf4 B = {0.f, 0.f, 0.f, 0.f};
    float A = 1.f;
    #pragma unroll
    for (int k = 0; k < 8; ++k) {
        const int j = wave * 8 + k;
        B = B * sa[j] + v4[k] * se[j];
        A *= sa[j];
    }
    seg[wave][lane] = B;
    if (lane == 0) asL[wave] = A;
    __syncthreads();

    vf4 W = seedL[lane];
    for (int p = 0; p < wave; ++p)
        W = W * asL[p] + seg[p][lane];

    float* Op = out + (size_t)(r0 + wave * 8) * D_DIM + 4 * lane;
    #pragma unroll
    for (int k = 0; k < 8; ++k) {
        const int j = wave * 8 + k;
        W = W * sa[j] + v4[k] * se[j];
        __builtin_nontemporal_store(W * sri[j],
                                    reinterpret_cast<vf4*>(Op + (size_t)k * D_DIM));
    }
}

// ================= launch ==================================================
extern "C" void kernel_launch(void* const* d_in, const int* in_sizes, int n_in,
                              void* d_out, int out_size, void* d_ws, size_t ws_size,
                              hipStream_t stream) {
    const float* K = (const float*)d_in[0];
    const float* V = (const float*)d_in[1];
    const float* q = (const float*)d_in[2];
    float* out = (float*)d_out;
    float* ws = (float*)d_ws;

    // fused-path workspace
    float* cmF = ws;                                   // 1024
    float* cuF = cmF + NB;                             // 1024
    float* TF  = cuF + NB;                             // 32*256 = 8192
    float* cwF = TF + (size_t)NSUP * D_DIM;            // 1024*256
    float* fb  = cwF + (size_t)NB * D_DIM;             // fallback region base

    void* kargs[8];
    kargs[0] = (void*)&K;  kargs[1] = (void*)&V;   kargs[2] = (void*)&q;
    kargs[3] = (void*)&cmF; kargs[4] = (void*)&cuF; kargs[5] = (void*)&cwF;
    kargs[6] = (void*)&TF;  kargs[7] = (void*)&out;

    hipError_t err = hipLaunchCooperativeKernel(
        reinterpret_cast<const void*>(&kFused),
        dim3(NB), dim3(256), kargs, 0, stream);

    if (err != hipSuccess) {
        (void)hipGetLastError();   // clear sticky error; fall back
        float* s_g  = fb;                                  // 65536
        float* cm   = s_g + L_TOTAL;                       // 2048
        float* cu   = cm + N_CHUNK;                        // 2048
        float* pm   = cu + N_CHUNK;                        // 2049 (+pad)
        float* pu   = pm + (N_CHUNK + 16);                 // 2049 (+pad)
        float* gsup = pu + (N_CHUNK + 16);                 // 64 (+pad)
        float* cw   = gsup + 128;                          // 2048*256
        float* pwl  = cw + (size_t)N_CHUNK * D_DIM;        // 2048*256
        float* T    = pwl + (size_t)N_CHUNK * D_DIM;       // 64*256

        kA_aggregate<<<N_CHUNK, 256, 0, stream>>>(K, V, q, s_g, cm, cu, cw);
        kCB_scan<<<N_SUPER, 256, 0, stream>>>(cm, cu, cw, pm, pu, gsup, pwl, T);
        kF_output<<<N_CHUNK, 256, 0, stream>>>(V, s_g, pm, pu, pwl, T, gsup, out);
    }
}

// Round 4
// 298.014 us; speedup vs baseline: 1.8756x; 1.8756x over previous
//
#include <hip/hip_runtime.h>
#include <math.h>

#define L_TOTAL 65536
#define D_DIM   256
#define RB      64                 // rows per block
#define NB      (L_TOTAL / RB)     // 1024 blocks

typedef float vf4 __attribute__((ext_vector_type(4)));

// Clear lookback flags (workspace is poisoned by the harness each iteration).
__global__ __launch_bounds__(256) void kClear(int* __restrict__ flag)
{
    const int i = blockIdx.x * 256 + threadIdx.x;
    if (i < NB) flag[i] = 0;
}

// Single-pass decoupled-lookback online-softmax scan.
// Block b owns rows [64b, 64b+64). Wave w owns rows [16w,16w+16);
// lane l owns cols [4l,4l+4). V is read ONCE and lives in v4[16] registers.
// flag[p]: 0 = nothing, 1 = aggregate (ma,ua,wa) ready, 2 = inclusive
// prefix (mi,ui,wi) ready. The (m,u,w) monoid is commutative, so the
// lookback window is combined order-free: pm = max m_p; beta_p = exp(m_p-pm);
// pu = sum beta_p u_p; pW = sum beta_p w_p.
__global__ __launch_bounds__(256) void kScan(
    const float* __restrict__ K, const float* __restrict__ V,
    const float* __restrict__ q,
    float* __restrict__ ma, float* __restrict__ ua,
    float* __restrict__ mi, float* __restrict__ ui,
    float* __restrict__ wa, float* __restrict__ wi,
    int* __restrict__ flag,
    float* __restrict__ out)
{
    const int t = threadIdx.x;
    const int b = blockIdx.x;
    const int r0 = b * RB;
    const int wave = t >> 6, lane = t & 63;

    __shared__ float s_lds[RB];
    __shared__ vf4  wbuf[4][64];        // partial-w / gather partials / segments
    __shared__ vf4  wlocL[64];          // block-local weighted V sum
    __shared__ vf4  seedL[64];          // exclusive vector prefix (frame pm)
    __shared__ float mwin[NB], uwin[NB];// lookback window (mwin becomes beta)
    __shared__ float mloc[RB], uloc[RB];
    __shared__ float sa[RB], se[RB], sri[RB];
    __shared__ float asL[4];
    __shared__ float pmS, puS;
    __shared__ int   nS, liS;

    // ---------------- phase 1: local aggregates ----------------------------
    vf4 v4[16];
    {
        const vf4* Vp = reinterpret_cast<const vf4*>(V + (size_t)(r0 + wave * 16) * D_DIM) + lane;
        #pragma unroll
        for (int k = 0; k < 16; ++k) v4[k] = Vp[(size_t)k * (D_DIM / 4)];

        const vf4 q4 = *reinterpret_cast<const vf4*>(q + 4 * lane);
        const vf4* Kp = reinterpret_cast<const vf4*>(K + (size_t)(r0 + wave * 16) * D_DIM) + lane;
        #pragma unroll
        for (int k = 0; k < 16; ++k) {
            const vf4 kv = __builtin_nontemporal_load(Kp + (size_t)k * (D_DIM / 4));
            float d = kv.x * q4.x + kv.y * q4.y + kv.z * q4.z + kv.w * q4.w;
            #pragma unroll
            for (int off = 32; off > 0; off >>= 1) d += __shfl_xor(d, off, 64);
            if (lane == 0) s_lds[wave * 16 + k] = d;
        }
    }
    __syncthreads();

    float m_b = -INFINITY;
    #pragma unroll
    for (int j = 0; j < RB; ++j) m_b = fmaxf(m_b, s_lds[j]);
    float u_b = 0.f;
    #pragma unroll
    for (int j = 0; j < RB; ++j) u_b += __expf(s_lds[j] - m_b);
    {
        vf4 pw = {0.f, 0.f, 0.f, 0.f};
        #pragma unroll
        for (int k = 0; k < 16; ++k)
            pw = pw + __expf(s_lds[wave * 16 + k] - m_b) * v4[k];
        wbuf[wave][lane] = pw;
    }
    __syncthreads();
    if (t < 64) {
        const vf4 w4 = (wbuf[0][t] + wbuf[1][t]) + (wbuf[2][t] + wbuf[3][t]);
        wlocL[t] = w4;
        reinterpret_cast<vf4*>(wa + (size_t)b * D_DIM)[t] = w4;
        if (t == 0) { ma[b] = m_b; ua[b] = u_b; }
    }
    __syncthreads();   // drains the wa/ma/ua stores (vmcnt(0) before barrier)
    if (t == 0)        // release flushes L2 -> aggregate visible device-wide
        __hip_atomic_store(&flag[b], 1, __ATOMIC_RELEASE, __HIP_MEMORY_SCOPE_AGENT);

    // ---------------- wave 1: seedless local row scan ----------------------
    if (wave == 1) {
        const float sv = s_lds[lane];
        float m = sv, u = 1.f;
        #pragma unroll
        for (int off = 1; off < 64; off <<= 1) {
            const float m1 = __shfl_up(m, off, 64);
            const float u1 = __shfl_up(u, off, 64);
            if (lane >= off) {
                const float mm = fmaxf(m1, m);
                u = u1 * __expf(m1 - mm) + u * __expf(m - mm);
                m = mm;
            }
        }
        mloc[lane] = m; uloc[lane] = u;
    }

    // ---------------- wave 0: 64-wide decoupled lookback -------------------
    if (wave == 0) {
        int n = 0, li = 0;
        if (b > 0) {
            int base = b - 1;
            while (true) {
                const int p = base - lane;      // p<0: virtual inclusive identity
                int f;
                while (true) {                  // wave-uniform relaxed poll
                    f = (p < 0) ? 2
                        : __hip_atomic_load(&flag[p], __ATOMIC_RELAXED, __HIP_MEMORY_SCOPE_AGENT);
                    if (__all(f != 0)) break;
                    __builtin_amdgcn_s_sleep(8);
                }
                // one acquire -> invalidates L1/L2 before payload reads
                (void)__hip_atomic_load(&flag[b - 1], __ATOMIC_ACQUIRE, __HIP_MEMORY_SCOPE_AGENT);
                const unsigned long long m2 = __ballot(f == 2);
                const int l2 = (m2 == 0) ? 64 : (__ffsll((long long)m2) - 1);
                float mv = -INFINITY, uv = 0.f;
                if (lane < l2)                 { mv = ma[p]; uv = ua[p]; }   // aggregates
                else if (lane == l2 && p >= 0) { mv = mi[p]; uv = ui[p]; }   // inclusive
                const int inc = (l2 < 64 && (base - l2) >= 0) ? 1 : 0;
                const int cnt = (l2 < 64) ? (l2 + inc) : 64;
                if (lane < cnt) { mwin[n + lane] = mv; uwin[n + lane] = uv; }
                n += cnt;
                if (l2 < 64) { li = inc; break; }
                base -= 64;
            }
        }
        // order-free combine of the window
        float mp = -INFINITY;
        for (int i = lane; i < n; i += 64) mp = fmaxf(mp, mwin[i]);
        #pragma unroll
        for (int off = 32; off > 0; off >>= 1) mp = fmaxf(mp, __shfl_xor(mp, off, 64));
        float up = 0.f;
        for (int i = lane; i < n; i += 64) {
            const float bt = __expf(mwin[i] - mp);
            mwin[i] = bt;                       // overwrite with beta
            up += bt * uwin[i];
        }
        #pragma unroll
        for (int off = 32; off > 0; off >>= 1) up += __shfl_xor(up, off, 64);
        if (lane == 0) { pmS = mp; puS = up; nS = n; liS = li; }
    }
    __syncthreads();

    // ---------------- all waves: parallel vector gather --------------------
    {
        const int n = nS, li = liS;
        vf4 acc = {0.f, 0.f, 0.f, 0.f};
        for (int i = wave; i < n; i += 4) {
            const int p = b - 1 - i;            // window entry i <-> block p
            const float bt = mwin[i];
            const float* basep = (li && i == n - 1) ? wi : wa;
            acc = acc + bt * reinterpret_cast<const vf4*>(basep + (size_t)p * D_DIM)[lane];
        }
        wbuf[wave][lane] = acc;
    }
    __syncthreads();

    // ---------------- seed, inclusive publish, row coefficients ------------
    if (t < 64) {
        const vf4 pW = (wbuf[0][t] + wbuf[1][t]) + (wbuf[2][t] + wbuf[3][t]);
        seedL[t] = pW;
        const float pm = pmS, pu = puS;
        const float m_inc = fmaxf(pm, m_b);
        const float b1 = __expf(pm - m_inc), b2 = __expf(m_b - m_inc);
        reinterpret_cast<vf4*>(wi + (size_t)b * D_DIM)[t] = pW * b1 + wlocL[t] * b2;
        if (t == 0) { mi[b] = m_inc; ui[b] = pu * b1 + u_b * b2; }

        const float ml = mloc[t], ul = uloc[t];
        const float m_row = fmaxf(pm, ml);
        const float u_row = pu * __expf(pm - m_row) + ul * __expf(ml - m_row);
        const float mprev = (t == 0) ? pm : fmaxf(pm, mloc[t - 1]);
        sa[t]  = __expf(mprev - m_row);     // row0 of block0: exp(-inf)=0
        se[t]  = __expf(s_lds[t] - m_row);
        sri[t] = 1.f / u_row;
    }
    __syncthreads();   // drains wi/mi/ui stores; sa/se/sri/seedL ready
    if (t == 0)
        __hip_atomic_store(&flag[b], 2, __ATOMIC_RELEASE, __HIP_MEMORY_SCOPE_AGENT);

    // ---------------- 4-segment vector recurrence + output -----------------
    vf4 B = {0.f, 0.f, 0.f, 0.f};
    float A = 1.f;
    #pragma unroll
    for (int k = 0; k < 16; ++k) {
        const int j = wave * 16 + k;
        B = B * sa[j] + v4[k] * se[j];
        A *= sa[j];
    }
    wbuf[wave][lane] = B;
    if (lane == 0) asL[wave] = A;
    __syncthreads();

    vf4 W = seedL[lane];
    for (int p = 0; p < wave; ++p)
        W = W * asL[p] + wbuf[p][lane];

    float* Op = out + (size_t)(r0 + wave * 16) * D_DIM + 4 * lane;
    #pragma unroll
    for (int k = 0; k < 16; ++k) {
        const int j = wave * 16 + k;
        W = W * sa[j] + v4[k] * se[j];
        __builtin_nontemporal_store(W * sri[j],
                                    reinterpret_cast<vf4*>(Op + (size_t)k * D_DIM));
    }
}

extern "C" void kernel_launch(void* const* d_in, const int* in_sizes, int n_in,
                              void* d_out, int out_size, void* d_ws, size_t ws_size,
                              hipStream_t stream) {
    const float* K = (const float*)d_in[0];
    const float* V = (const float*)d_in[1];
    const float* q = (const float*)d_in[2];
    float* out = (float*)d_out;

    float* ws  = (float*)d_ws;
    int*   flag = (int*)ws;                         // 1024 (ints)
    float* ma  = ws + 1024;                         // 1024
    float* ua  = ma + NB;                           // 1024
    float* mi  = ua + NB;                           // 1024
    float* ui  = mi + NB;                           // 1024
    float* wa  = ui + NB;                           // 1024*256 (16B-aligned)
    float* wi  = wa + (size_t)NB * D_DIM;           // 1024*256

    kClear<<<(NB + 255) / 256, 256, 0, stream>>>(flag);
    kScan<<<NB, 256, 0, stream>>>(K, V, q, ma, ua, mi, ui, wa, wi, flag, out);
}

// Round 5
// 191.420 us; speedup vs baseline: 2.9201x; 1.5569x over previous
//
#include <hip/hip_runtime.h>
#include <math.h>

#define L_TOTAL 65536
#define D_DIM   256
#define C_ROWS  32                    // rows per chunk
#define N_CHUNK (L_TOTAL / C_ROWS)    // 2048
#define SUPER   32                    // chunks per super-chunk
#define N_SUPER (N_CHUNK / SUPER)     // 64

typedef float vf4 __attribute__((ext_vector_type(4)));

// ---------------- kA: per-chunk aggregates, fully float4 -------------------
// Layout: wave w owns rows [8w, 8w+8); lane l owns cols [4l, 4l+4).
// K loads are PLAIN (not nontemporal): K+V = 128 MB fits the 256 MB LLC,
// so K stays LLC-resident across iterations like V does (round-4 insight:
// NT loads bypass LLC allocation -> 65.5 MB HBM re-fetch per iteration).
__global__ __launch_bounds__(256) void kA_aggregate(
    const float* __restrict__ K, const float* __restrict__ V,
    const float* __restrict__ q,
    float* __restrict__ s_g, float* __restrict__ cm,
    float* __restrict__ cu, float* __restrict__ cw)
{
    const int t = threadIdx.x;
    const int c = blockIdx.x;
    const int r0 = c * C_ROWS;
    const int wave = t >> 6, lane = t & 63;

    __shared__ float s_lds[C_ROWS];
    __shared__ vf4  pw_lds[4][64];    // 4 KB partial-w

    // V first: 8 vf4 per thread
    vf4 v4[8];
    const vf4* Vp = reinterpret_cast<const vf4*>(V + (size_t)(r0 + wave * 8) * D_DIM) + lane;
    #pragma unroll
    for (int k = 0; k < 8; ++k) v4[k] = Vp[(size_t)k * (D_DIM / 4)];

    // K: plain cached vf4 loads, dot with q, wave-reduce
    const vf4 q4 = *reinterpret_cast<const vf4*>(q + 4 * lane);
    const vf4* Kp = reinterpret_cast<const vf4*>(K + (size_t)(r0 + wave * 8) * D_DIM) + lane;
    #pragma unroll
    for (int k = 0; k < 8; ++k) {
        const vf4 kv = Kp[(size_t)k * (D_DIM / 4)];
        float d = kv.x * q4.x + kv.y * q4.y + kv.z * q4.z + kv.w * q4.w;
        #pragma unroll
        for (int off = 32; off > 0; off >>= 1) d += __shfl_xor(d, off, 64);
        if (lane == 0) s_lds[wave * 8 + k] = d;
    }
    __syncthreads();

    if (t < C_ROWS) s_g[r0 + t] = s_lds[t];

    float m_c = -INFINITY;
    #pragma unroll
    for (int j = 0; j < C_ROWS; ++j) m_c = fmaxf(m_c, s_lds[j]);
    float u_c = 0.f;
    #pragma unroll
    for (int j = 0; j < C_ROWS; ++j) u_c += __expf(s_lds[j] - m_c);

    // per-wave partial weighted sum over its 8 rows
    vf4 pw = {0.f, 0.f, 0.f, 0.f};
    #pragma unroll
    for (int k = 0; k < 8; ++k) {
        const float cf = __expf(s_lds[wave * 8 + k] - m_c);
        pw = pw + cf * v4[k];
    }
    pw_lds[wave][lane] = pw;
    __syncthreads();

    if (t < 64) {
        const vf4 w4 = (pw_lds[0][t] + pw_lds[1][t]) + (pw_lds[2][t] + pw_lds[3][t]);
        reinterpret_cast<vf4*>(cw + (size_t)c * D_DIM)[t] = w4;
    }
    if (t == 0) { cm[c] = m_c; cu[c] = u_c; }
}

// ---------------- kCB: redundant scalar scan + per-super vector scan -------
__global__ __launch_bounds__(256) void kCB_scan(
    const float* __restrict__ cm, const float* __restrict__ cu,
    const float* __restrict__ cw,
    float* __restrict__ pm, float* __restrict__ pu,
    float* __restrict__ gsup,
    float* __restrict__ pwl, float* __restrict__ T)
{
    const int t = threadIdx.x;
    const int S = blockIdx.x;
    __shared__ float Lm[256], Lu[256];
    __shared__ float pmL[N_CHUNK + 1];
    __shared__ float ca[SUPER], cb[SUPER];

    float am[8], au[8];
    float M = -INFINITY, U = 0.f;
    #pragma unroll
    for (int j = 0; j < 8; ++j) {
        am[j] = cm[8 * t + j]; au[j] = cu[8 * t + j];
        const float mm = fmaxf(M, am[j]);
        U = U * __expf(M - mm) + au[j] * __expf(am[j] - mm);
        M = mm;
    }
    Lm[t] = M; Lu[t] = U;
    float Mi = M, Ui = U;
    __syncthreads();
    for (int off = 1; off < 256; off <<= 1) {
        float m1 = 0.f, u1 = 0.f;
        const bool act = (t >= off);
        if (act) { m1 = Lm[t - off]; u1 = Lu[t - off]; }
        __syncthreads();
        if (act) {
            const float mm = fmaxf(m1, Mi);
            Ui = u1 * __expf(m1 - mm) + Ui * __expf(Mi - mm);
            Mi = mm;
            Lm[t] = Mi; Lu[t] = Ui;
        }
        __syncthreads();
    }
    float Me = (t == 0) ? -INFINITY : Lm[t - 1];
    float Ue = (t == 0) ? 0.f : Lu[t - 1];
    #pragma unroll
    for (int j = 0; j < 8; ++j) {
        pmL[8 * t + j] = Me;
        if (S == 0) { pm[8 * t + j] = Me; pu[8 * t + j] = Ue; }
        const float mm = fmaxf(Me, am[j]);
        Ue = Ue * __expf(Me - mm) + au[j] * __expf(am[j] - mm);
        Me = mm;
    }
    if (t == 255) {
        pmL[N_CHUNK] = Me;
        if (S == 0) { pm[N_CHUNK] = Me; pu[N_CHUNK] = Ue; }
    }
    __syncthreads();

    float wv[SUPER];
    const float* cwp = cw + (size_t)S * SUPER * D_DIM + t;
    #pragma unroll
    for (int j = 0; j < SUPER; ++j) wv[j] = cwp[(size_t)j * D_DIM];

    if (t < SUPER) {
        const int c = S * SUPER + t;
        ca[t] = __expf(pmL[c] - pmL[c + 1]);   // c=0: exp(-inf)=0
        cb[t] = __expf(cm[c] - pmL[c + 1]);
    }
    if (t == 0)
        gsup[S] = __expf(pmL[S * SUPER] - pmL[S * SUPER + SUPER]); // S=0: 0
    __syncthreads();

    float PW = 0.f;
    float* pwlp = pwl + (size_t)S * SUPER * D_DIM + t;
    #pragma unroll
    for (int j = 0; j < SUPER; ++j) {
        pwlp[(size_t)j * D_DIM] = PW;
        PW = PW * ca[j] + wv[j] * cb[j];
    }
    T[(size_t)S * D_DIM + t] = PW;
}

// ---------------- kF: float4 everywhere via 4-segment row scan -------------
__global__ __launch_bounds__(256) void kF_output(
    const float* __restrict__ V, const float* __restrict__ s_g,
    const float* __restrict__ pm, const float* __restrict__ pu,
    const float* __restrict__ pwl, const float* __restrict__ T,
    const float* __restrict__ gsup,
    float* __restrict__ out)
{
    const int t = threadIdx.x;
    const int c = blockIdx.x;
    const int S = c / SUPER;
    const int r0 = c * C_ROWS;
    const int wave = t >> 6, lane = t & 63;

    __shared__ float sa[C_ROWS], se[C_ROWS], sri[C_ROWS];
    __shared__ vf4 seedL[64];       // 1 KB: cross-chunk seed per column-quad
    __shared__ vf4 seg[4][64];      // 4 KB: per-wave segment results
    __shared__ float asL[4];        // per-wave decay products

    // V: 8 vf4 per thread (independent, issued first)
    vf4 v4[8];
    const vf4* Vp = reinterpret_cast<const vf4*>(V + (size_t)(r0 + wave * 8) * D_DIM) + lane;
    #pragma unroll
    for (int k = 0; k < 8; ++k) v4[k] = Vp[(size_t)k * (D_DIM / 4)];

    if (wave == 0) {
        // barrier-free shuffle scan over the 32 rows
        const float pmc = pm[c];
        const float puc = pu[c];
        float s_val = -INFINITY;
        if (lane < C_ROWS) s_val = s_g[r0 + lane];
        float m = s_val, u = 1.0f;
        #pragma unroll
        for (int off = 1; off < C_ROWS; off <<= 1) {
            const float m1 = __shfl_up(m, off, 32);
            const float u1 = __shfl_up(u, off, 32);
            if ((lane & 31) >= off) {
                const float mm = fmaxf(m1, m);
                u = u1 * __expf(m1 - mm) + u * __expf(m - mm);
                m = mm;
            }
        }
        const float m_row = fmaxf(pmc, m);
        const float u_row = puc * __expf(pmc - m_row) + u * __expf(m - m_row);
        const float m_prev_raw = __shfl_up(m_row, 1, 32);
        const float m_prev = ((lane & 31) == 0) ? pmc : m_prev_raw;
        if (lane < C_ROWS) {
            sa[lane]  = __expf(m_prev - m_row);   // row0 of chunk0: exp(-inf)=0
            se[lane]  = __expf(s_val - m_row);
            sri[lane] = 1.0f / u_row;
        }
    } else if (wave == 1) {
        // cross-super exclusive vector prefix in vf4, published via LDS
        const float pmc = pm[c];
        const float pmS = pm[S * SUPER];
        vf4 SW = {0.f, 0.f, 0.f, 0.f};
        const vf4* T4 = reinterpret_cast<const vf4*>(T) + lane;
        #pragma unroll 8
        for (int Sp = 0; Sp < S; ++Sp) {
            const float g = gsup[Sp];
            SW = SW * g + T4[(size_t)Sp * (D_DIM / 4)];
        }
        const float gf = (c == 0) ? 0.f : __expf(pmS - pmc);
        const vf4 sp = reinterpret_cast<const vf4*>(pwl + (size_t)c * D_DIM)[lane];
        seedL[lane] = SW * gf + sp;
    }
    __syncthreads();   // sa/se/sri + seedL ready

    // pass 1: zero-init local segment scan over this wave's 8 rows
    vf4 B = {0.f, 0.f, 0.f, 0.f};
    float A = 1.f;
    #pragma unroll
    for (int k = 0; k < 8; ++k) {
        const int j = wave * 8 + k;
        B = B * sa[j] + v4[k] * se[j];
        A *= sa[j];
    }
    seg[wave][lane] = B;
    if (lane == 0) asL[wave] = A;
    __syncthreads();

    // cross-wave combine: exact serial fold of segment summaries
    vf4 W = seedL[lane];
    for (int p = 0; p < wave; ++p)
        W = W * asL[p] + seg[p][lane];

    // pass 2: final recurrence with correct W_in, vf4 NT stores
    float* Op = out + (size_t)r0 * D_DIM + (size_t)(wave * 8) * D_DIM + 4 * lane;
    #pragma unroll
    for (int k = 0; k < 8; ++k) {
        const int j = wave * 8 + k;
        W = W * sa[j] + v4[k] * se[j];
        __builtin_nontemporal_store(W * sri[j],
                                    reinterpret_cast<vf4*>(Op + (size_t)k * D_DIM));
    }
}

extern "C" void kernel_launch(void* const* d_in, const int* in_sizes, int n_in,
                              void* d_out, int out_size, void* d_ws, size_t ws_size,
                              hipStream_t stream) {
    const float* K = (const float*)d_in[0];
    const float* V = (const float*)d_in[1];
    const float* q = (const float*)d_in[2];
    float* out = (float*)d_out;

    float* ws   = (float*)d_ws;
    float* s_g  = ws;                                  // 65536
    float* cm   = s_g + L_TOTAL;                       // 2048
    float* cu   = cm + N_CHUNK;                        // 2048
    float* pm   = cu + N_CHUNK;                        // 2049 (+pad)
    float* pu   = pm + (N_CHUNK + 16);                 // 2049 (+pad)
    float* gsup = pu + (N_CHUNK + 16);                 // 64 (+pad)
    float* cw   = gsup + 128;                          // 2048*256
    float* pwl  = cw + (size_t)N_CHUNK * D_DIM;        // 2048*256
    float* T    = pwl + (size_t)N_CHUNK * D_DIM;       // 64*256

    kA_aggregate<<<N_CHUNK, 256, 0, stream>>>(K, V, q, s_g, cm, cu, cw);
    kCB_scan<<<N_SUPER, 256, 0, stream>>>(cm, cu, cw, pm, pu, gsup, pwl, T);
    kF_output<<<N_CHUNK, 256, 0, stream>>>(V, s_g, pm, pu, pwl, T, gsup, out);
}

// Round 6
// 182.261 us; speedup vs baseline: 3.0668x; 1.0503x over previous
//
#include <hip/hip_runtime.h>
#include <math.h>

#define L_TOTAL 65536
#define D_DIM   256
#define C_ROWS  32                    // rows per chunk
#define N_CHUNK (L_TOTAL / C_ROWS)    // 2048
#define SUPER   32                    // chunks per super-chunk
#define N_SUPER (N_CHUNK / SUPER)     // 64

typedef float vf4 __attribute__((ext_vector_type(4)));

// ---------------- kA: per-chunk aggregates ---------------------------------
// Wave w owns rows [8w, 8w+8); lane l owns cols [4l, 4l+4).
// K: NT loads (always an HBM stream; NT avoids L2 pollution — round-5 A/B).
// Dot reduction: row-merging butterfly — 10 shuffles for 8 rows (vs 48),
// all 8 K loads issued up front for MLP.
__global__ __launch_bounds__(256) void kA_aggregate(
    const float* __restrict__ K, const float* __restrict__ V,
    const float* __restrict__ q,
    float* __restrict__ s_g, float* __restrict__ cm,
    float* __restrict__ cu, float* __restrict__ cw)
{
    const int t = threadIdx.x;
    const int c = blockIdx.x;
    const int r0 = c * C_ROWS;
    const int wave = t >> 6, lane = t & 63;

    __shared__ float s_lds[C_ROWS];
    __shared__ vf4  pw_lds[4][64];    // 4 KB partial-w

    // K first (HBM latency ~900cy), all 8 rows in flight
    const vf4* Kp = reinterpret_cast<const vf4*>(K + (size_t)(r0 + wave * 8) * D_DIM) + lane;
    vf4 kv[8];
    #pragma unroll
    for (int k = 0; k < 8; ++k)
        kv[k] = __builtin_nontemporal_load(Kp + (size_t)k * (D_DIM / 4));

    // V second (LLC-supplied)
    vf4 v4[8];
    const vf4* Vp = reinterpret_cast<const vf4*>(V + (size_t)(r0 + wave * 8) * D_DIM) + lane;
    #pragma unroll
    for (int k = 0; k < 8; ++k) v4[k] = Vp[(size_t)k * (D_DIM / 4)];

    const vf4 q4 = *reinterpret_cast<const vf4*>(q + 4 * lane);
    float p[8];
    #pragma unroll
    for (int k = 0; k < 8; ++k)
        p[k] = kv[k].x * q4.x + kv[k].y * q4.y + kv[k].z * q4.z + kv[k].w * q4.w;

    // row-merging butterfly: level 1 (mask 32), rows pair (2i, 2i+1)
    const int b5 = (lane >> 5) & 1, b4 = (lane >> 4) & 1, b3 = (lane >> 3) & 1;
    float tr[4];
    #pragma unroll
    for (int i = 0; i < 4; ++i) {
        const float a = b5 ? p[2 * i + 1] : p[2 * i];
        const float o = b5 ? p[2 * i]     : p[2 * i + 1];
        tr[i] = a + __shfl_xor(o, 32, 64);
    }
    // level 2 (mask 16)
    float ur[2];
    #pragma unroll
    for (int i = 0; i < 2; ++i) {
        const float a = b4 ? tr[2 * i + 1] : tr[2 * i];
        const float o = b4 ? tr[2 * i]     : tr[2 * i + 1];
        ur[i] = a + __shfl_xor(o, 16, 64);
    }
    // level 3 (mask 8)
    float vr;
    {
        const float a = b3 ? ur[1] : ur[0];
        const float o = b3 ? ur[0] : ur[1];
        vr = a + __shfl_xor(o, 8, 64);
    }
    // levels 4-6: same-row lanes
    vr += __shfl_xor(vr, 4, 64);
    vr += __shfl_xor(vr, 2, 64);
    vr += __shfl_xor(vr, 1, 64);
    // lane holds full sum of row j = 4*b3 + 2*b4 + b5
    if ((lane & 7) == 0)
        s_lds[wave * 8 + (4 * b3 + 2 * b4 + b5)] = vr;
    __syncthreads();

    if (t < C_ROWS) s_g[r0 + t] = s_lds[t];

    float m_c = -INFINITY;
    #pragma unroll
    for (int j = 0; j < C_ROWS; ++j) m_c = fmaxf(m_c, s_lds[j]);
    float u_c = 0.f;
    #pragma unroll
    for (int j = 0; j < C_ROWS; ++j) u_c += __expf(s_lds[j] - m_c);

    vf4 pw = {0.f, 0.f, 0.f, 0.f};
    #pragma unroll
    for (int k = 0; k < 8; ++k) {
        const float cf = __expf(s_lds[wave * 8 + k] - m_c);
        pw = pw + cf * v4[k];
    }
    pw_lds[wave][lane] = pw;
    __syncthreads();

    if (t < 64) {
        const vf4 w4 = (pw_lds[0][t] + pw_lds[1][t]) + (pw_lds[2][t] + pw_lds[3][t]);
        reinterpret_cast<vf4*>(cw + (size_t)c * D_DIM)[t] = w4;
    }
    if (t == 0) { cm[c] = m_c; cu[c] = u_c; }
}

// ---------------- kCB: redundant scalar scan + per-super vector scan -------
__global__ __launch_bounds__(256) void kCB_scan(
    const float* __restrict__ cm, const float* __restrict__ cu,
    const float* __restrict__ cw,
    float* __restrict__ pm, float* __restrict__ pu,
    float* __restrict__ gsup,
    float* __restrict__ pwl, float* __restrict__ T)
{
    const int t = threadIdx.x;
    const int S = blockIdx.x;
    __shared__ float Lm[256], Lu[256];
    __shared__ float pmL[N_CHUNK + 1];
    __shared__ float ca[SUPER], cb[SUPER];

    float am[8], au[8];
    float M = -INFINITY, U = 0.f;
    #pragma unroll
    for (int j = 0; j < 8; ++j) {
        am[j] = cm[8 * t + j]; au[j] = cu[8 * t + j];
        const float mm = fmaxf(M, am[j]);
        U = U * __expf(M - mm) + au[j] * __expf(am[j] - mm);
        M = mm;
    }
    Lm[t] = M; Lu[t] = U;
    float Mi = M, Ui = U;
    __syncthreads();
    for (int off = 1; off < 256; off <<= 1) {
        float m1 = 0.f, u1 = 0.f;
        const bool act = (t >= off);
        if (act) { m1 = Lm[t - off]; u1 = Lu[t - off]; }
        __syncthreads();
        if (act) {
            const float mm = fmaxf(m1, Mi);
            Ui = u1 * __expf(m1 - mm) + Ui * __expf(Mi - mm);
            Mi = mm;
            Lm[t] = Mi; Lu[t] = Ui;
        }
        __syncthreads();
    }
    float Me = (t == 0) ? -INFINITY : Lm[t - 1];
    float Ue = (t == 0) ? 0.f : Lu[t - 1];
    #pragma unroll
    for (int j = 0; j < 8; ++j) {
        pmL[8 * t + j] = Me;
        if (S == 0) { pm[8 * t + j] = Me; pu[8 * t + j] = Ue; }
        const float mm = fmaxf(Me, am[j]);
        Ue = Ue * __expf(Me - mm) + au[j] * __expf(am[j] - mm);
        Me = mm;
    }
    if (t == 255) {
        pmL[N_CHUNK] = Me;
        if (S == 0) { pm[N_CHUNK] = Me; pu[N_CHUNK] = Ue; }
    }
    __syncthreads();

    float wv[SUPER];
    const float* cwp = cw + (size_t)S * SUPER * D_DIM + t;
    #pragma unroll
    for (int j = 0; j < SUPER; ++j) wv[j] = cwp[(size_t)j * D_DIM];

    if (t < SUPER) {
        const int c = S * SUPER + t;
        ca[t] = __expf(pmL[c] - pmL[c + 1]);   // c=0: exp(-inf)=0
        cb[t] = __expf(cm[c] - pmL[c + 1]);
    }
    if (t == 0)
        gsup[S] = __expf(pmL[S * SUPER] - pmL[S * SUPER + SUPER]); // S=0: 0
    __syncthreads();

    float PW = 0.f;
    float* pwlp = pwl + (size_t)S * SUPER * D_DIM + t;
    #pragma unroll
    for (int j = 0; j < SUPER; ++j) {
        pwlp[(size_t)j * D_DIM] = PW;
        PW = PW * ca[j] + wv[j] * cb[j];
    }
    T[(size_t)S * D_DIM + t] = PW;
}

// ---------------- kF: float4 everywhere via 4-segment row scan -------------
// Seed gather de-serialized: SW = sum G[Sp]*T[Sp] with G from a shfl_down
// suffix-product scan (no division; g=0 safe) — independent T loads.
__global__ __launch_bounds__(256) void kF_output(
    const float* __restrict__ V, const float* __restrict__ s_g,
    const float* __restrict__ pm, const float* __restrict__ pu,
    const float* __restrict__ pwl, const float* __restrict__ T,
    const float* __restrict__ gsup,
    float* __restrict__ out)
{
    const int t = threadIdx.x;
    const int c = blockIdx.x;
    const int S = c / SUPER;
    const int r0 = c * C_ROWS;
    const int wave = t >> 6, lane = t & 63;

    __shared__ float sa[C_ROWS], se[C_ROWS], sri[C_ROWS];
    __shared__ vf4 seedL[64];
    __shared__ vf4 seg[4][64];
    __shared__ float asL[4];
    __shared__ float GL[N_SUPER];

    // V: 8 vf4 per thread (independent, issued first)
    vf4 v4[8];
    const vf4* Vp = reinterpret_cast<const vf4*>(V + (size_t)(r0 + wave * 8) * D_DIM) + lane;
    #pragma unroll
    for (int k = 0; k < 8; ++k) v4[k] = Vp[(size_t)k * (D_DIM / 4)];

    if (wave == 0) {
        const float pmc = pm[c];
        const float puc = pu[c];
        float s_val = -INFINITY;
        if (lane < C_ROWS) s_val = s_g[r0 + lane];
        float m = s_val, u = 1.0f;
        #pragma unroll
        for (int off = 1; off < C_ROWS; off <<= 1) {
            const float m1 = __shfl_up(m, off, 32);
            const float u1 = __shfl_up(u, off, 32);
            if ((lane & 31) >= off) {
                const float mm = fmaxf(m1, m);
                u = u1 * __expf(m1 - mm) + u * __expf(m - mm);
                m = mm;
            }
        }
        const float m_row = fmaxf(pmc, m);
        const float u_row = puc * __expf(pmc - m_row) + u * __expf(m - m_row);
        const float m_prev_raw = __shfl_up(m_row, 1, 32);
        const float m_prev = ((lane & 31) == 0) ? pmc : m_prev_raw;
        if (lane < C_ROWS) {
            sa[lane]  = __expf(m_prev - m_row);   // row0 of chunk0: exp(-inf)=0
            se[lane]  = __expf(s_val - m_row);
            sri[lane] = 1.0f / u_row;
        }
    } else if (wave == 1) {
        // suffix products: G_l = prod_{l<r<S} gsup[r]  (h_r = 1 for r >= S)
        float h = (lane < S) ? gsup[lane] : 1.0f;
        #pragma unroll
        for (int off = 1; off < 64; off <<= 1) {
            const float tt = __shfl_down(h, off, 64);
            if (lane + off < 64) h *= tt;
        }
        float G = __shfl_down(h, 1, 64);
        if (lane == 63) G = 1.0f;
        GL[lane] = G;

        const float pmc = pm[c];
        const float pmS = pm[S * SUPER];
        vf4 SW = {0.f, 0.f, 0.f, 0.f};
        const vf4* T4 = reinterpret_cast<const vf4*>(T) + lane;
        #pragma unroll 8
        for (int Sp = 0; Sp < S; ++Sp)
            SW = SW + GL[Sp] * T4[(size_t)Sp * (D_DIM / 4)];
        const float gf = (c == 0) ? 0.f : __expf(pmS - pmc);
        const vf4 sp = reinterpret_cast<const vf4*>(pwl + (size_t)c * D_DIM)[lane];
        seedL[lane] = SW * gf + sp;
    }
    __syncthreads();   // sa/se/sri + seedL ready

    vf4 B = {0.f, 0.f, 0.f, 0.f};
    float A = 1.f;
    #pragma unroll
    for (int k = 0; k < 8; ++k) {
        const int j = wave * 8 + k;
        B = B * sa[j] + v4[k] * se[j];
        A *= sa[j];
    }
    seg[wave][lane] = B;
    if (lane == 0) asL[wave] = A;
    __syncthreads();

    vf4 W = seedL[lane];
    for (int p = 0; p < wave; ++p)
        W = W * asL[p] + seg[p][lane];

    float* Op = out + (size_t)(r0 + wave * 8) * D_DIM + 4 * lane;
    #pragma unroll
    for (int k = 0; k < 8; ++k) {
        const int j = wave * 8 + k;
        W = W * sa[j] + v4[k] * se[j];
        __builtin_nontemporal_store(W * sri[j],
                                    reinterpret_cast<vf4*>(Op + (size_t)k * D_DIM));
    }
}

extern "C" void kernel_launch(void* const* d_in, const int* in_sizes, int n_in,
                              void* d_out, int out_size, void* d_ws, size_t ws_size,
                              hipStream_t stream) {
    const float* K = (const float*)d_in[0];
    const float* V = (const float*)d_in[1];
    const float* q = (const float*)d_in[2];
    float* out = (float*)d_out;

    float* ws   = (float*)d_ws;
    float* s_g  = ws;                                  // 65536
    float* cm   = s_g + L_TOTAL;                       // 2048
    float* cu   = cm + N_CHUNK;                        // 2048
    float* pm   = cu + N_CHUNK;                        // 2049 (+pad)
    float* pu   = pm + (N_CHUNK + 16);                 // 2049 (+pad)
    float* gsup = pu + (N_CHUNK + 16);                 // 64 (+pad)
    float* cw   = gsup + 128;                          // 2048*256
    float* pwl  = cw + (size_t)N_CHUNK * D_DIM;        // 2048*256
    float* T    = pwl + (size_t)N_CHUNK * D_DIM;       // 64*256

    kA_aggregate<<<N_CHUNK, 256, 0, stream>>>(K, V, q, s_g, cm, cu, cw);
    kCB_scan<<<N_SUPER, 256, 0, stream>>>(cm, cu, cw, pm, pu, gsup, pwl, T);
    kF_output<<<N_CHUNK, 256, 0, stream>>>(V, s_g, pm, pu, pwl, T, gsup, out);
}